// Round 1
// baseline (407.028 us; speedup 1.0000x reference)
//
#include <hip/hip_runtime.h>
#include <math.h>

// AvU loss: per-row softmax stats over [N, 32] f32 logits, 4 global sums,
// final scalar -log(avu + eps). Memory-bound: ~272 MB read -> ~45 us floor.

#define AVU_EPS 1e-10f

__global__ __launch_bounds__(256) void avu_main_kernel(
    const float* __restrict__ logits,
    const int* __restrict__ labels,
    const float* __restrict__ unc_th_p,
    double* __restrict__ sums,  // [4] = n_ac, n_au, n_ic, n_iu
    int N)
{
    const float unc_th = unc_th_p[0];

    float acc0 = 0.f, acc1 = 0.f, acc2 = 0.f, acc3 = 0.f;

    const int stride = gridDim.x * blockDim.x;
    for (int row = blockIdx.x * blockDim.x + threadIdx.x; row < N; row += stride) {
        const float4* rp = (const float4*)(logits + (size_t)row * 32);
        float4 v[8];
#pragma unroll
        for (int j = 0; j < 8; ++j) v[j] = rp[j];

        // max + argmax (first occurrence via strict >)
        float m = v[0].x;
        int idx = 0;
#pragma unroll
        for (int j = 0; j < 8; ++j) {
            const float* f = (const float*)&v[j];
#pragma unroll
            for (int k = 0; k < 4; ++k) {
                const int i = j * 4 + k;
                const float x = f[k];
                if (x > m) { m = x; idx = i; }
            }
        }

        // S = sum exp(x-m); dot = sum exp(x-m)*(x-m)
        float S = 0.f, dot = 0.f;
#pragma unroll
        for (int j = 0; j < 8; ++j) {
            const float* f = (const float*)&v[j];
#pragma unroll
            for (int k = 0; k < 4; ++k) {
                const float d = f[k] - m;
                const float e = __expf(d);
                S += e;
                dot += e * d;
            }
        }

        const float rS   = 1.0f / S;
        const float conf = rS;                     // max prob = exp(0)/S
        const float unc  = __logf(S) - dot * rS;   // -sum p log p
        const float t    = tanhf(unc);

        const bool accurate = (labels[row] == idx);
        const bool certain  = (unc <= unc_th);

        const float a = accurate ? conf : (1.0f - conf);
        const float w = certain ? (1.0f - t) : t;
        const float val = a * w;

        acc0 += ( accurate &&  certain) ? val : 0.f;  // n_ac
        acc1 += ( accurate && !certain) ? val : 0.f;  // n_au
        acc2 += (!accurate &&  certain) ? val : 0.f;  // n_ic
        acc3 += (!accurate && !certain) ? val : 0.f;  // n_iu
    }

    // wave64 shuffle reduction
#pragma unroll
    for (int off = 32; off > 0; off >>= 1) {
        acc0 += __shfl_down(acc0, off);
        acc1 += __shfl_down(acc1, off);
        acc2 += __shfl_down(acc2, off);
        acc3 += __shfl_down(acc3, off);
    }

    __shared__ float red[4][4];  // [wave][category]
    const int wave = threadIdx.x >> 6;
    const int lane = threadIdx.x & 63;
    if (lane == 0) {
        red[wave][0] = acc0;
        red[wave][1] = acc1;
        red[wave][2] = acc2;
        red[wave][3] = acc3;
    }
    __syncthreads();

    if (threadIdx.x == 0) {
        double s0 = 0.0, s1 = 0.0, s2 = 0.0, s3 = 0.0;
#pragma unroll
        for (int w = 0; w < 4; ++w) {
            s0 += (double)red[w][0];
            s1 += (double)red[w][1];
            s2 += (double)red[w][2];
            s3 += (double)red[w][3];
        }
        atomicAdd(&sums[0], s0);
        atomicAdd(&sums[1], s1);
        atomicAdd(&sums[2], s2);
        atomicAdd(&sums[3], s3);
    }
}

__global__ void avu_final_kernel(const double* __restrict__ sums,
                                 float* __restrict__ out)
{
    const double n_ac = sums[0];
    const double n_au = sums[1];
    const double n_ic = sums[2];
    const double n_iu = sums[3];
    const double avu = (n_ac + n_iu) / (n_ac + n_au + n_ic + n_iu + 1e-10);
    out[0] = (float)(-log(avu + 1e-10));
}

extern "C" void kernel_launch(void* const* d_in, const int* in_sizes, int n_in,
                              void* d_out, int out_size, void* d_ws, size_t ws_size,
                              hipStream_t stream)
{
    const float* logits   = (const float*)d_in[0];
    const int*   labels   = (const int*)d_in[1];
    const float* unc_th   = (const float*)d_in[2];
    float*       out      = (float*)d_out;
    double*      sums     = (double*)d_ws;

    const int N = in_sizes[1];  // labels element count = number of rows

    // ws is re-poisoned to 0xAA before every call — zero the 4 accumulators.
    hipMemsetAsync(d_ws, 0, 4 * sizeof(double), stream);

    // 2048 blocks x 256 threads: 8 blocks/CU (full 32 waves/CU), 4 rows/thread,
    // and only 2048 atomics per accumulator address.
    avu_main_kernel<<<2048, 256, 0, stream>>>(logits, labels, unc_th, sums, N);
    avu_final_kernel<<<1, 1, 0, stream>>>(sums, out);
}

// Round 2
// 376.840 us; speedup vs baseline: 1.0801x; 1.0801x over previous
//
#include <hip/hip_runtime.h>
#include <math.h>

// AvU loss over [N, 32] f32 logits.
// Layout: 8 lanes per row -> each wave global_load_dwordx4 reads 1 KiB
// contiguous (8 rows x 32 floats). Row stats via 8-lane xor-shuffle
// butterflies. Per-block partials in d_ws, tiny final-reduce kernel.

__global__ __launch_bounds__(256) void avu_main(
    const float* __restrict__ logits,
    const int* __restrict__ labels,
    const float* __restrict__ unc_th_p,
    float4* __restrict__ partials,   // [gridDim.x]
    int N)
{
    const float unc_th = unc_th_p[0];
    const float4* __restrict__ p4 = (const float4*)logits;

    const int lane = threadIdx.x & 63;
    const int wave = threadIdx.x >> 6;
    const int sub  = lane & 7;    // which float4 within the row
    const int rgrp = lane >> 3;   // which row within the 8-row group

    const int wavesPerBlock = blockDim.x >> 6;
    const int W  = blockIdx.x * wavesPerBlock + wave;   // global wave id
    const int TW = gridDim.x * wavesPerBlock;           // total waves

    const int G   = (N + 7) >> 3;          // number of 8-row groups
    const int gpw = (G + TW - 1) / TW;     // groups per wave (contiguous span)
    const int g0  = W * gpw;

    const int totalF4 = N * 8;             // N*32 floats / 4

    float acc0 = 0.f, acc1 = 0.f, acc2 = 0.f, acc3 = 0.f;

    // software pipeline: prefetch group g0
    float4 v = make_float4(0.f, 0.f, 0.f, 0.f);
    if (g0 < G) {
        const int f4 = g0 * 64 + lane;
        if (f4 < totalF4) v = p4[f4];
    }

    for (int i = 0; i < gpw; ++i) {
        const int g = g0 + i;
        if (g >= G) break;

        // prefetch next group before processing current
        float4 vn = make_float4(0.f, 0.f, 0.f, 0.f);
        if (i + 1 < gpw && g + 1 < G) {
            const int f4 = (g + 1) * 64 + lane;
            if (f4 < totalF4) vn = p4[f4];
        }

        const int row   = (g << 3) + rgrp;
        const bool valid = (row < N);
        const int lab = valid ? labels[row] : -1;

        // per-lane max/argmax over its 4 elements (first-occurrence ties)
        const int base = sub << 2;
        float m = v.x; int mi = base;
        if (v.y > m) { m = v.y; mi = base + 1; }
        if (v.z > m) { m = v.z; mi = base + 2; }
        if (v.w > m) { m = v.w; mi = base + 3; }

        // 8-lane butterfly argmax (tie -> smaller index)
#pragma unroll
        for (int mask = 1; mask <= 4; mask <<= 1) {
            const float om = __shfl_xor(m, mask);
            const int   oi = __shfl_xor(mi, mask);
            if (om > m || (om == m && oi < mi)) { m = om; mi = oi; }
        }

        // S = sum exp(x-m); dot = sum exp(x-m)*(x-m)
        const float d0 = v.x - m, d1 = v.y - m, d2 = v.z - m, d3 = v.w - m;
        const float e0 = __expf(d0), e1 = __expf(d1);
        const float e2 = __expf(d2), e3 = __expf(d3);
        float S   = (e0 + e1) + (e2 + e3);
        float dot = (e0 * d0 + e1 * d1) + (e2 * d2 + e3 * d3);
#pragma unroll
        for (int mask = 1; mask <= 4; mask <<= 1) {
            S   += __shfl_xor(S, mask);
            dot += __shfl_xor(dot, mask);
        }

        const float rS   = 1.0f / S;
        const float conf = rS;                     // max prob = exp(0)/S
        const float unc  = __logf(S) - dot * rS;   // entropy, in [0, log 32]
        // tanh(u) = 1 - 2/(e^{2u}+1), u >= 0 so no overflow
        const float t = 1.0f - 2.0f / (__expf(2.0f * unc) + 1.0f);

        const bool accurate = (lab == mi);
        const bool certain  = (unc <= unc_th);

        const float a = accurate ? conf : (1.0f - conf);
        const float w = certain ? (1.0f - t) : t;
        float val = a * w;
        val = (sub == 0 && valid) ? val : 0.f;     // one contribution per row

        acc0 += ( accurate &&  certain) ? val : 0.f;  // n_ac
        acc1 += ( accurate && !certain) ? val : 0.f;  // n_au
        acc2 += (!accurate &&  certain) ? val : 0.f;  // n_ic
        acc3 += (!accurate && !certain) ? val : 0.f;  // n_iu

        v = vn;
    }

    // full-wave butterfly reduction
#pragma unroll
    for (int mask = 1; mask <= 32; mask <<= 1) {
        acc0 += __shfl_xor(acc0, mask);
        acc1 += __shfl_xor(acc1, mask);
        acc2 += __shfl_xor(acc2, mask);
        acc3 += __shfl_xor(acc3, mask);
    }

    __shared__ float4 red[4];
    if (lane == 0) red[wave] = make_float4(acc0, acc1, acc2, acc3);
    __syncthreads();

    if (threadIdx.x == 0) {
        float4 r = red[0];
        for (int w2 = 1; w2 < wavesPerBlock; ++w2) {
            const float4 q = red[w2];
            r.x += q.x; r.y += q.y; r.z += q.z; r.w += q.w;
        }
        partials[blockIdx.x] = r;
    }
}

__global__ __launch_bounds__(64) void avu_final(
    const float4* __restrict__ partials, int nPart,
    float* __restrict__ out)
{
    double s0 = 0.0, s1 = 0.0, s2 = 0.0, s3 = 0.0;
    for (int i = threadIdx.x; i < nPart; i += 64) {
        const float4 p = partials[i];
        s0 += (double)p.x; s1 += (double)p.y;
        s2 += (double)p.z; s3 += (double)p.w;
    }
#pragma unroll
    for (int mask = 1; mask <= 32; mask <<= 1) {
        s0 += __shfl_xor(s0, mask);
        s1 += __shfl_xor(s1, mask);
        s2 += __shfl_xor(s2, mask);
        s3 += __shfl_xor(s3, mask);
    }
    if (threadIdx.x == 0) {
        const double avu = (s0 + s3) / (s0 + s1 + s2 + s3 + 1e-10);
        out[0] = (float)(-log(avu + 1e-10));
    }
}

extern "C" void kernel_launch(void* const* d_in, const int* in_sizes, int n_in,
                              void* d_out, int out_size, void* d_ws, size_t ws_size,
                              hipStream_t stream)
{
    const float* logits = (const float*)d_in[0];
    const int*   labels = (const int*)d_in[1];
    const float* unc_th = (const float*)d_in[2];
    float*       out    = (float*)d_out;
    float4*      parts  = (float4*)d_ws;

    const int N = in_sizes[1];   // labels element count = rows
    const int BLOCKS = 2048;     // 8 blocks/CU, 8192 waves, 32 KiB/wave span

    avu_main<<<BLOCKS, 256, 0, stream>>>(logits, labels, unc_th, parts, N);
    avu_final<<<1, 64, 0, stream>>>(parts, BLOCKS, out);
}